// Round 10
// baseline (190.540 us; speedup 1.0000x reference)
//
#include <hip/hip_runtime.h>
#include <hip/hip_bf16.h>
#include <math.h>

#define NQ     16384
#define CDIM   256
#define NHEADS 8
#define NPTS   8
#define NLVL   2
#define HH     128
#define WWID   128
#define DHEAD  32
#define NCAT   384   // fused off(256) + attn(128) projection width

// padded fp8 value-map geometry: (l, h, 130, 130, 32) fp8, zero border
#define PW        130
#define CELLB     32                    // bytes per cell (32 dims x fp8)
#define ROWB      (PW * CELLB)          // 4160 B per padded row
#define MAPB      (PW * PW * CELLB)     // 540800 B per (l,h) map
#define BORDER_BLKS 16                  // one block per (l,h) map border
#define TRANS_BLKS  224

typedef __bf16 bf16_t;
typedef __bf16 bf16x8 __attribute__((ext_vector_type(8)));
typedef float  f32x4  __attribute__((ext_vector_type(4)));
typedef float  f32x2  __attribute__((ext_vector_type(2)));

typedef __attribute__((address_space(1))) const uint32_t gau32;
typedef __attribute__((address_space(3))) uint32_t lau32;

__device__ __forceinline__ bf16_t f2b(float f) { return (bf16_t)f; }

__device__ __forceinline__ bf16x8 cvt8(float4 a, float4 b) {
    bf16x8 v;
    v[0] = f2b(a.x); v[1] = f2b(a.y); v[2] = f2b(a.z); v[3] = f2b(a.w);
    v[4] = f2b(b.x); v[5] = f2b(b.y); v[6] = f2b(b.z); v[7] = f2b(b.w);
    return v;
}

// ---------------------------------------------------------------------------
// Tiny prep: zero ONLY the v2 pad border + transpose weights to bf16.
// W_val rows PERMUTED: n -> p(n) = (n&~63) | ((n&3)<<4) | ((n&63)>>2)
// ---------------------------------------------------------------------------
__global__ __launch_bounds__(256) void prep_k(const float* __restrict__ W_val,
                                              const float* __restrict__ W_off,
                                              const float* __restrict__ W_attn,
                                              const float* __restrict__ W_out,
                                              unsigned char* __restrict__ v2,
                                              bf16_t* __restrict__ Wt_val,
                                              bf16_t* __restrict__ Wt_qa,
                                              bf16_t* __restrict__ Wt_out) {
    const int b = blockIdx.x;
    if (b < BORDER_BLKS) {
        unsigned char* map = v2 + (size_t)b * MAPB;
        for (int i = threadIdx.x; i < 516; i += 256) {
            int y, x;
            if (i < 130)      { y = 0;        x = i;       }
            else if (i < 260) { y = 129;      x = i - 130; }
            else if (i < 388) { y = i - 259;  x = 0;       }
            else              { y = i - 387;  x = 129;     }
            uint4* p = reinterpret_cast<uint4*>(map + (size_t)y * ROWB + x * CELLB);
            p[0] = make_uint4(0, 0, 0, 0);
            p[1] = make_uint4(0, 0, 0, 0);
        }
        return;
    }
    {
        const int tb = b - BORDER_BLKS;
        const float* W; bf16_t* Wt; int N, t; bool permute = false;
        if (tb < 64)       { W = W_val;  Wt = Wt_val;            N = 256; t = tb;       permute = true; }
        else if (tb < 128) { W = W_off;  Wt = Wt_qa;             N = 256; t = tb - 64;  }
        else if (tb < 160) { W = W_attn; Wt = Wt_qa + 256 * 256; N = 128; t = tb - 128; }
        else               { W = W_out;  Wt = Wt_out;            N = 256; t = tb - 160; }
        const int ntn = N >> 5;
        const int k0 = (t / ntn) * 32, n0 = (t % ntn) * 32;
        const int tx = threadIdx.x & 31, ty = threadIdx.x >> 5;   // 32 x 8
        __shared__ float s[32][33];
#pragma unroll
        for (int i = 0; i < 4; ++i)
            s[ty + 8 * i][tx] = W[(size_t)(k0 + ty + 8 * i) * N + n0 + tx];
        __syncthreads();
#pragma unroll
        for (int i = 0; i < 4; ++i) {
            const int n = n0 + ty + 8 * i;
            const int p = permute ? ((n & ~63) | ((n & 3) << 4) | ((n & 63) >> 2)) : n;
            Wt[(size_t)p * 256 + k0 + tx] = f2b(s[tx][ty + 8 * i]);
        }
    }
}

// ---------------------------------------------------------------------------
// Projection GEMM body, 64x128 tile (R9 config: 1792 blocks, 7/CU grid for
// cold-HBM latency hiding). A-only LDS (16 KB dbuf); B read DIRECTLY from
// global per k-step (weights L2-resident, shared by all blocks). No
// global_load_lds => barriers wait only lgkmcnt; A reg-loads use counted
// vmcnt at their storeA, after the MFMA block.
//   AMODE 1 (v-proj): 2-deep A prefetch, nt=4 fully unrolled.
//   AMODE 2 (q-proj): 1-deep (ra+rb staging), VGPR-bounded.
// Swizzle invariant (A): LDS[row][granule g] holds global k-granule g^(row&7).
// PERM_V epilogue: stored col s = (wave&1)*32 + j*16 + fr within 64-group
// corresponds to ORIGINAL col n = fr*4 + (wave&1)*2 + j -> ushort store.
// ---------------------------------------------------------------------------
template <int AMODE, bool PERM_V>
__device__ __forceinline__ void proj_body(bf16_t (&As)[2][64][64],
                                          int bidx, int bidy,
                                          const float* __restrict__ Af0,
                                          const float* __restrict__ Af1,
                                          const bf16_t* __restrict__ Bt,
                                          const float* __restrict__ bias,
                                          const float* __restrict__ bias2,
                                          int Nsplit,
                                          void* __restrict__ Cout,
                                          int N, int K) {
    const int tid  = threadIdx.x;
    const int wave = tid >> 6;
    const int lane = tid & 63;
    const int rowBase = bidy * 64;
    const int colBase = bidx * 128;
    const int wn = wave * 32;
    const int fr = lane & 15;
    const int fq = lane >> 4;

    f32x4 acc[4][2] = {};

    const int lrow = lane >> 3;                       // 0..7
    const int scol = ((lane & 7) ^ lrow) * 8;         // swizzled k-offset (elems)

    auto loadA = [&](int t, float4 (&ra)[2][2]) {
#pragma unroll
        for (int tt = 0; tt < 2; ++tt) {
            const float* src =
                Af0 + (size_t)(rowBase + wave * 16 + tt * 8 + lrow) * K + t * 64 + scol;
            ra[tt][0] = *reinterpret_cast<const float4*>(src);
            ra[tt][1] = *reinterpret_cast<const float4*>(src + 4);
        }
    };
    auto loadA2 = [&](int t, float4 (&rb)[2][2]) {
#pragma unroll
        for (int tt = 0; tt < 2; ++tt) {
            const float* src =
                Af1 + (size_t)(rowBase + wave * 16 + tt * 8 + lrow) * K + t * 64 + scol;
            rb[tt][0] = *reinterpret_cast<const float4*>(src);
            rb[tt][1] = *reinterpret_cast<const float4*>(src + 4);
        }
    };
    auto storeA = [&](int buf, float4 (&ra)[2][2]) {
#pragma unroll
        for (int tt = 0; tt < 2; ++tt)
            *reinterpret_cast<bf16x8*>(
                &As[buf][wave * 16 + tt * 8 + lrow][(lane & 7) * 8]) =
                cvt8(ra[tt][0], ra[tt][1]);
    };
    auto storeAsum = [&](int buf, float4 (&ra)[2][2], float4 (&rb)[2][2]) {
#pragma unroll
        for (int tt = 0; tt < 2; ++tt) {
            float4 a = ra[tt][0], c = ra[tt][1];
            a.x += rb[tt][0].x; a.y += rb[tt][0].y;
            a.z += rb[tt][0].z; a.w += rb[tt][0].w;
            c.x += rb[tt][1].x; c.y += rb[tt][1].y;
            c.z += rb[tt][1].z; c.w += rb[tt][1].w;
            *reinterpret_cast<bf16x8*>(
                &As[buf][wave * 16 + tt * 8 + lrow][(lane & 7) * 8]) = cvt8(a, c);
        }
    };
    auto compute = [&](int c, int t) {
#pragma unroll
        for (int ks = 0; ks < 2; ++ks) {
            const int gk = ((ks * 4 + fq) ^ (fr & 7)) * 8;  // A: swizzled granule
            const int kb = t * 64 + (ks * 4 + fq) * 8;      // B: natural granule
            bf16x8 af[4], bfr[2];
#pragma unroll
            for (int i = 0; i < 4; ++i)
                af[i] = *reinterpret_cast<const bf16x8*>(&As[c][i * 16 + fr][gk]);
#pragma unroll
            for (int j = 0; j < 2; ++j)
                bfr[j] = *reinterpret_cast<const bf16x8*>(
                    &Bt[(size_t)(colBase + wn + j * 16 + fr) * K + kb]);
#pragma unroll
            for (int i = 0; i < 4; ++i)
#pragma unroll
                for (int j = 0; j < 2; ++j)
                    acc[i][j] = __builtin_amdgcn_mfma_f32_16x16x32_bf16(af[i], bfr[j],
                                                                        acc[i][j], 0, 0, 0);
        }
    };

    if constexpr (AMODE == 1) {
        float4 ra0[2][2], ra1[2][2];
        loadA(0, ra0);
        loadA(1, ra1);
        storeA(0, ra0);
        __syncthreads();
        loadA(2, ra0);
        compute(0, 0);
        storeA(1, ra1);
        __syncthreads();
        loadA(3, ra1);
        compute(1, 1);
        storeA(0, ra0);
        __syncthreads();
        compute(0, 2);
        storeA(1, ra1);
        __syncthreads();
        compute(1, 3);
    } else {
        float4 ra[2][2], rb[2][2];
        loadA(0, ra); loadA2(0, rb);
        storeAsum(0, ra, rb);
        __syncthreads();
        for (int t = 0; t < 4; ++t) {
            const int c = t & 1, n = c ^ 1;
            if (t + 1 < 4) { loadA(t + 1, ra); loadA2(t + 1, rb); }
            compute(c, t);
            if (t + 1 < 4) {
                storeAsum(n, ra, rb);
                __syncthreads();
            }
        }
    }

    if (PERM_V) {
        const int w2 = wave & 1;
        const int n0 = colBase + (wave >> 1) * 64 + fr * 4 + w2 * 2; // orig col, j=0
        const float bv0 = bias[n0], bv1 = bias[n0 + 1];
        const int hh = (n0 >> 5) & 7;
        const int dbase = n0 & 31;
        unsigned char* outp = (unsigned char*)Cout;
#pragma unroll
        for (int i = 0; i < 4; ++i) {
#pragma unroll
            for (int r = 0; r < 4; ++r) {
                const int row = rowBase + i * 16 + fq * 4 + r;
                const int lv = row >> 14, cell = row & 16383;
                const int y = cell >> 7, x = cell & 127;
                uint32_t pk = __builtin_amdgcn_cvt_pk_fp8_f32(
                    acc[i][0][r] + bv0, acc[i][1][r] + bv1, 0, false);
                *reinterpret_cast<unsigned short*>(
                    outp + (size_t)(lv * NHEADS + hh) * MAPB
                         + (size_t)(y + 1) * ROWB + (x + 1) * CELLB + dbase) =
                    (unsigned short)pk;
            }
        }
        return;
    }

    // epilogue: D[row = fq*4 + r][col = fr] per 16x16 tile, bf16 out
#pragma unroll
    for (int j = 0; j < 2; ++j) {
        const int col = colBase + wn + j * 16 + fr;
        const float bv = (col < Nsplit) ? bias[col] : bias2[col - Nsplit];
#pragma unroll
        for (int i = 0; i < 4; ++i) {
#pragma unroll
            for (int r = 0; r < 4; ++r) {
                const int row = rowBase + i * 16 + fq * 4 + r;
                ((bf16_t*)Cout)[(size_t)row * N + col] = f2b(acc[i][j][r] + bv);
            }
        }
    }
}

// ---------------------------------------------------------------------------
// Fused projections straight from fp32 inputs, 64x128 tiles, 1792 blocks.
// blocks 0..1023:    value @ Wt_val -> padded fp8 v2
// blocks 1024..1791: (query+query_pos) @ [W_off|W_attn] -> cbuf
// ---------------------------------------------------------------------------
__global__ __launch_bounds__(256, 4) void fused_proj_k(const float* __restrict__ value,
                                                       const float* __restrict__ query,
                                                       const float* __restrict__ query_pos,
                                                       const bf16_t* __restrict__ Wt_val,
                                                       const bf16_t* __restrict__ Wt_qa,
                                                       const float* __restrict__ b_val,
                                                       const float* __restrict__ b_off,
                                                       const float* __restrict__ b_attn,
                                                       unsigned char* __restrict__ v2,
                                                       bf16_t* __restrict__ cbuf) {
    __shared__ __align__(16) bf16_t As[2][64][64];
    const int b = blockIdx.x;
    if (b < 1024) {
        const int bidy = (b >> 4) * 8 + (b & 7);   // 0..511
        const int bidx = (b >> 3) & 1;             // adjacent pair shares rows
        proj_body<1, true>(As, bidx, bidy, value, nullptr,
                           Wt_val, b_val, b_val, 256, v2, CDIM, CDIM);
    } else {
        const int b2 = b - 1024;                   // 0..767
        const int bidy = (b2 / 24) * 8 + (b2 & 7); // 0..255
        const int bidx = (b2 >> 3) % 3;            // adjacent triple shares rows
        proj_body<2, false>(As, bidx, bidy, query, query_pos,
                            Wt_qa, b_off, b_attn, 256, cbuf, NCAT, CDIM);
    }
}

// ---------------------------------------------------------------------------
// FUSED sampling + output projection. 1024 blocks x 16 queries.
// Phase 1: R1-config sampler — 2 threads/(q,h), 16 dims each, uint4 taps
//   (16q x 8h x 2 = 256 threads). Result -> LDS Ls[16][256] bf16 (8 KB),
//   stored with the proj XOR-granule swizzle: granule c at row q lives at
//   c ^ (q&7). Clamped taps land on zero cells.
// Phase 2: one barrier, then out[16x256] = Ls @ Wt_out + b_out + query.
//   A from LDS (swizzled read g^(row&7), 2-way max bank alias = free);
//   B (Wt_out, 128 KB) direct from global/L2 per R7/R8. 4 waves x 64 cols.
// Kills the tmp round-trip (17 MB) + one launch + outproj's standalone
// latency exposure.
// ---------------------------------------------------------------------------
__device__ __forceinline__ void acc_tap4(uint4 u, float w, f32x2* acc2) {
    acc2[0] += __builtin_amdgcn_cvt_pk_f32_fp8((int)u.x, false) * w;
    acc2[1] += __builtin_amdgcn_cvt_pk_f32_fp8((int)u.x, true)  * w;
    acc2[2] += __builtin_amdgcn_cvt_pk_f32_fp8((int)u.y, false) * w;
    acc2[3] += __builtin_amdgcn_cvt_pk_f32_fp8((int)u.y, true)  * w;
    acc2[4] += __builtin_amdgcn_cvt_pk_f32_fp8((int)u.z, false) * w;
    acc2[5] += __builtin_amdgcn_cvt_pk_f32_fp8((int)u.z, true)  * w;
    acc2[6] += __builtin_amdgcn_cvt_pk_f32_fp8((int)u.w, false) * w;
    acc2[7] += __builtin_amdgcn_cvt_pk_f32_fp8((int)u.w, true)  * w;
}

__global__ __launch_bounds__(256, 4) void sample_out_k(const unsigned char* __restrict__ v2,
                                                       const bf16_t* __restrict__ cbuf,
                                                       const float* __restrict__ refp,
                                                       const bf16_t* __restrict__ Wt_out,
                                                       const float* __restrict__ b_out,
                                                       const float* __restrict__ query,
                                                       float* __restrict__ out) {
    __shared__ __align__(16) bf16_t Ls[16][256];
    const int qblk = blockIdx.x;      // 1024 blocks, 16 queries each
    const int tid  = threadIdx.x;

    // ---- phase 1: sample ----
    {
        const int ck   = tid & 1;         // 16-dim half
        const int h    = (tid >> 1) & 7;
        const int qloc = tid >> 4;        // 0..15
        const int q    = qblk * 16 + qloc;

        const bf16_t* qrow = cbuf + (size_t)q * NCAT;
        const float4 rp = *reinterpret_cast<const float4*>(refp + (size_t)q * 4);

        const bf16_t* attp = qrow + 256 + h * 16;
        bf16x8 A0 = *reinterpret_cast<const bf16x8*>(attp);
        bf16x8 A1 = *reinterpret_cast<const bf16x8*>(attp + 8);
        float e[16];
#pragma unroll
        for (int i = 0; i < 8; ++i) { e[i] = (float)A0[i]; e[8 + i] = (float)A1[i]; }
        float m = e[0];
#pragma unroll
        for (int i = 1; i < 16; ++i) m = fmaxf(m, e[i]);
        float s = 0.f;
#pragma unroll
        for (int i = 0; i < 16; ++i) { e[i] = __expf(e[i] - m); s += e[i]; }
        const float inv = 1.f / s;
#pragma unroll
        for (int i = 0; i < 16; ++i) e[i] *= inv;

        f32x2 acc2[8] = {};

#pragma unroll
        for (int l = 0; l < NLVL; ++l) {
            const float bx = (l == 0 ? rp.x : rp.z) * (float)WWID - 0.5f;
            const float by = (l == 0 ? rp.y : rp.w) * (float)HH - 0.5f;
            const unsigned char* base = v2 + (size_t)(l * NHEADS + h) * MAPB
                                           + 131 * CELLB + ck * 16;
            const bf16_t* offp = qrow + h * 32 + l * 16;
            bf16x8 o0 = *reinterpret_cast<const bf16x8*>(offp);
            bf16x8 o1 = *reinterpret_cast<const bf16x8*>(offp + 8);
            float ox[8], oy[8];
#pragma unroll
            for (int i = 0; i < 4; ++i) {
                ox[i]     = (float)o0[2 * i];  oy[i]     = (float)o0[2 * i + 1];
                ox[4 + i] = (float)o1[2 * i];  oy[4 + i] = (float)o1[2 * i + 1];
            }

#pragma unroll
            for (int p = 0; p < NPTS; ++p) {
                const float px = bx + ox[p];
                const float py = by + oy[p];
                const float w  = e[l * 8 + p];
                const float x0f = floorf(px), y0f = floorf(py);
                const int x0 = (int)x0f, y0 = (int)y0f;
                const float wx1 = px - x0f, wy1 = py - y0f;
                const float wx0 = 1.f - wx1, wy0 = 1.f - wy1;
                const int x0c = min(max(x0, -1), 128);
                const int x1c = min(max(x0 + 1, -1), 128);
                const int y0c = min(max(y0, -1), 128);
                const int y1c = min(max(y0 + 1, -1), 128);
                const unsigned char* r0 = base + y0c * ROWB;
                const unsigned char* r1 = base + y1c * ROWB;
                uint4 u00 = *reinterpret_cast<const uint4*>(r0 + x0c * CELLB);
                uint4 u10 = *reinterpret_cast<const uint4*>(r0 + x1c * CELLB);
                uint4 u01 = *reinterpret_cast<const uint4*>(r1 + x0c * CELLB);
                uint4 u11 = *reinterpret_cast<const uint4*>(r1 + x1c * CELLB);
                const float wy0w = w * wy0, wy1w = w * wy1;
                acc_tap4(u00, wy0w * wx0, acc2);
                acc_tap4(u10, wy0w * wx1, acc2);
                acc_tap4(u01, wy1w * wx0, acc2);
                acc_tap4(u11, wy1w * wx1, acc2);
            }
        }

        bf16x8 ov0, ov1;
#pragma unroll
        for (int i = 0; i < 4; ++i) {
            ov0[2 * i]     = f2b(acc2[i].x);
            ov0[2 * i + 1] = f2b(acc2[i].y);
            ov1[2 * i]     = f2b(acc2[4 + i].x);
            ov1[2 * i + 1] = f2b(acc2[4 + i].y);
        }
        // LDS store with XOR-granule swizzle: granule c -> c ^ (qloc&7)
        const int c0 = h * 4 + ck * 2;                 // 0..31 (8 bf16 granules)
        const int sw = qloc & 7;
        *reinterpret_cast<bf16x8*>(&Ls[qloc][(c0 ^ sw) * 8])       = ov0;
        *reinterpret_cast<bf16x8*>(&Ls[qloc][((c0 + 1) ^ sw) * 8]) = ov1;
    }

    __syncthreads();

    // ---- phase 2: 16x256 GEMM, A = Ls (swizzled), B = Wt_out direct ----
    {
        const int wave = tid >> 6;       // 4 waves x 64 cols
        const int lane = tid & 63;
        const int fr = lane & 15;
        const int fq = lane >> 4;
        const int colBase = wave * 64;
        const int K = 256;

        f32x4 acc[4] = {};
#pragma unroll
        for (int c32 = 0; c32 < 8; ++c32) {           // K in 32-chunks
            const int gA = c32 * 4 + fq;              // natural granule
            bf16x8 af = *reinterpret_cast<const bf16x8*>(
                &Ls[fr][(gA ^ (fr & 7)) * 8]);        // row = fr
            const int kb = c32 * 32 + fq * 8;
            bf16x8 bfr[4];
#pragma unroll
            for (int j = 0; j < 4; ++j)
                bfr[j] = *reinterpret_cast<const bf16x8*>(
                    &Wt_out[(size_t)(colBase + j * 16 + fr) * K + kb]);
#pragma unroll
            for (int j = 0; j < 4; ++j)
                acc[j] = __builtin_amdgcn_mfma_f32_16x16x32_bf16(af, bfr[j],
                                                                 acc[j], 0, 0, 0);
        }

#pragma unroll
        for (int j = 0; j < 4; ++j) {
            const int col = colBase + j * 16 + fr;
            const float bv = b_out[col];
#pragma unroll
            for (int r = 0; r < 4; ++r) {
                const int row = qblk * 16 + fq * 4 + r;
                out[(size_t)row * CDIM + col] =
                    acc[j][r] + bv + query[(size_t)row * CDIM + col];
            }
        }
    }
}

// ---------------------------------------------------------------------------
extern "C" void kernel_launch(void* const* d_in, const int* in_sizes, int n_in,
                              void* d_out, int out_size, void* d_ws, size_t ws_size,
                              hipStream_t stream) {
    const float* query     = (const float*)d_in[0];
    const float* query_pos = (const float*)d_in[1];
    const float* value     = (const float*)d_in[2];
    const float* refp      = (const float*)d_in[3];
    // d_in[4] spatial_shapes: static 128x128, hard-coded
    const float* W_off  = (const float*)d_in[5];
    const float* b_off  = (const float*)d_in[6];
    const float* W_attn = (const float*)d_in[7];
    const float* b_attn = (const float*)d_in[8];
    const float* W_val  = (const float*)d_in[9];
    const float* b_val  = (const float*)d_in[10];
    const float* W_out  = (const float*)d_in[11];
    const float* b_out  = (const float*)d_in[12];
    float* out = (float*)d_out;

    char* ws = (char*)d_ws;
    unsigned char* v2 = (unsigned char*)(ws);             //  8,654,848 B (padded fp8)
    bf16_t* cbuf    = (bf16_t*)(ws + 8654848);            // 12,582,912 B (16384x384 bf16)
    bf16_t* Wt_val  = (bf16_t*)(ws + 29626368);           //    131,072 B (col-permuted)
    bf16_t* Wt_qa   = (bf16_t*)(ws + 29757440);           //    196,608 B (384x256)
    bf16_t* Wt_out  = (bf16_t*)(ws + 29954048);           //    131,072 B
    // total 30,085,120 B

    // border-zero v2 + transpose weights (tiny)
    prep_k<<<BORDER_BLKS + TRANS_BLKS, 256, 0, stream>>>(
        W_val, W_off, W_attn, W_out, v2, Wt_val, Wt_qa, Wt_out);
    // v2 (padded fp8 per-head maps) + cbuf (off|attn logits, bf16),
    // fp32->bf16 conversion fused into A staging; 64x128 tiles, 1792 blocks,
    // A-only LDS (16 KB), B direct from L2, 2-deep A prefetch on v-proj
    fused_proj_k<<<1792, 256, 0, stream>>>(value, query, query_pos,
                                           Wt_val, Wt_qa, b_val, b_off, b_attn,
                                           v2, cbuf);
    // FUSED softmax + bilinear sampling + output projection (+ residual)
    sample_out_k<<<1024, 256, 0, stream>>>(v2, cbuf, refp,
                                           Wt_out, b_out, query, out);
}

// Round 11
// 175.530 us; speedup vs baseline: 1.0855x; 1.0855x over previous
//
#include <hip/hip_runtime.h>
#include <hip/hip_bf16.h>
#include <math.h>

#define NQ     16384
#define CDIM   256
#define NHEADS 8
#define NPTS   8
#define NLVL   2
#define HH     128
#define WWID   128
#define DHEAD  32
#define NCAT   384   // fused off(256) + attn(128) projection width

// padded fp8 value-map geometry: (l, h, 130, 130, 32) fp8, zero border
#define PW        130
#define CELLB     32                    // bytes per cell (32 dims x fp8)
#define ROWB      (PW * CELLB)          // 4160 B per padded row
#define MAPB      (PW * PW * CELLB)     // 540800 B per (l,h) map
#define BORDER_BLKS 16                  // one block per (l,h) map border
#define TRANS_BLKS  224

typedef __bf16 bf16_t;
typedef __bf16 bf16x8 __attribute__((ext_vector_type(8)));
typedef float  f32x4  __attribute__((ext_vector_type(4)));
typedef float  f32x2  __attribute__((ext_vector_type(2)));

typedef __attribute__((address_space(1))) const uint32_t gau32;
typedef __attribute__((address_space(3))) uint32_t lau32;

__device__ __forceinline__ bf16_t f2b(float f) { return (bf16_t)f; }

__device__ __forceinline__ bf16x8 cvt8(float4 a, float4 b) {
    bf16x8 v;
    v[0] = f2b(a.x); v[1] = f2b(a.y); v[2] = f2b(a.z); v[3] = f2b(a.w);
    v[4] = f2b(b.x); v[5] = f2b(b.y); v[6] = f2b(b.z); v[7] = f2b(b.w);
    return v;
}

// ---------------------------------------------------------------------------
// Tiny prep: zero ONLY the v2 pad border (interior is fully overwritten by
// the v-proj GEMM) + transpose weights to bf16.
// W_val rows PERMUTED: n -> p(n) = (n&~63) | ((n&3)<<4) | ((n&63)>>2)
// ---------------------------------------------------------------------------
__global__ __launch_bounds__(256) void prep_k(const float* __restrict__ W_val,
                                              const float* __restrict__ W_off,
                                              const float* __restrict__ W_attn,
                                              const float* __restrict__ W_out,
                                              unsigned char* __restrict__ v2,
                                              bf16_t* __restrict__ Wt_val,
                                              bf16_t* __restrict__ Wt_qa,
                                              bf16_t* __restrict__ Wt_out) {
    const int b = blockIdx.x;
    if (b < BORDER_BLKS) {
        // border ring of map b: rows 0 and 129 (130 cells each),
        // cols 0 and 129 for y = 1..128 (128 cells each) => 516 cells.
        unsigned char* map = v2 + (size_t)b * MAPB;
        for (int i = threadIdx.x; i < 516; i += 256) {
            int y, x;
            if (i < 130)      { y = 0;        x = i;       }
            else if (i < 260) { y = 129;      x = i - 130; }
            else if (i < 388) { y = i - 259;  x = 0;       }
            else              { y = i - 387;  x = 129;     }
            uint4* p = reinterpret_cast<uint4*>(map + (size_t)y * ROWB + x * CELLB);
            p[0] = make_uint4(0, 0, 0, 0);
            p[1] = make_uint4(0, 0, 0, 0);
        }
        return;
    }
    {
        const int tb = b - BORDER_BLKS;
        const float* W; bf16_t* Wt; int N, t; bool permute = false;
        if (tb < 64)       { W = W_val;  Wt = Wt_val;            N = 256; t = tb;       permute = true; }
        else if (tb < 128) { W = W_off;  Wt = Wt_qa;             N = 256; t = tb - 64;  }
        else if (tb < 160) { W = W_attn; Wt = Wt_qa + 256 * 256; N = 128; t = tb - 128; }
        else               { W = W_out;  Wt = Wt_out;            N = 256; t = tb - 160; }
        const int ntn = N >> 5;
        const int k0 = (t / ntn) * 32, n0 = (t % ntn) * 32;
        const int tx = threadIdx.x & 31, ty = threadIdx.x >> 5;   // 32 x 8
        __shared__ float s[32][33];
#pragma unroll
        for (int i = 0; i < 4; ++i)
            s[ty + 8 * i][tx] = W[(size_t)(k0 + ty + 8 * i) * N + n0 + tx];
        __syncthreads();
#pragma unroll
        for (int i = 0; i < 4; ++i) {
            const int n = n0 + ty + 8 * i;
            const int p = permute ? ((n & ~63) | ((n & 3) << 4) | ((n & 63) >> 2)) : n;
            Wt[(size_t)p * 256 + k0 + tx] = f2b(s[tx][ty + 8 * i]);
        }
    }
}

// ---------------------------------------------------------------------------
// 128x128-tile GEMM body, 2-phase double-buffered pipeline (one barrier per
// k-step). B staged via global_load_lds (bf16 weights). A staging:
//   AMODE 0: bf16 source via global_load_lds (full-line, XOR-swizzled src)
//   AMODE 1: fp32 source, reg-staged + cvt -> swizzled LDS (same layout)
//   AMODE 2: fp32 + fp32 sum (query + query_pos), reg-staged + cvt
// Swizzle invariant: LDS[row][granule g] holds global k-granule g^(row&7).
// PERM_V: packs 4 fp8 -> 1 dword into the padded v2 map.
// ---------------------------------------------------------------------------
template <int AMODE, bool OUT_BF16, bool ADD_SRC, bool PERM_V>
__device__ __forceinline__ void gemm_body(bf16_t (&As)[2][128][64], bf16_t (&Bs)[2][128][64],
                                          int bidx, int bidy,
                                          const bf16_t* __restrict__ Abf,
                                          const float* __restrict__ Af0,
                                          const float* __restrict__ Af1,
                                          const bf16_t* __restrict__ Bt,
                                          const float* __restrict__ bias,
                                          const float* __restrict__ bias2,
                                          int Nsplit,
                                          const float* __restrict__ addsrc,
                                          void* __restrict__ Cout,
                                          int N, int K) {
    const int tid  = threadIdx.x;
    const int wave = tid >> 6;
    const int lane = tid & 63;
    const int rowBase = bidy * 128;
    const int colBase = bidx * 128;
    const int wm = (wave & 1) * 64;
    const int wn = (wave >> 1) * 64;
    const int fr = lane & 15;
    const int fq = lane >> 4;

    f32x4 acc[4][4] = {};

    const int lrow = lane >> 3;                       // 0..7
    const int scol = ((lane & 7) ^ lrow) * 8;         // swizzled k-offset (elems)
    const int nt = K >> 6;                            // 64-wide k-tiles

    float4 ra[4][2], rb[4][2];

    auto issueA = [&](int t, int buf) {
        if constexpr (AMODE == 0) {
#pragma unroll
            for (int tt = 0; tt < 4; ++tt) {
                const bf16_t* src =
                    Abf + (size_t)(rowBase + wave * 32 + tt * 8 + lrow) * K + t * 64 + scol;
                __builtin_amdgcn_global_load_lds((gau32*)src,
                                                 (lau32*)&As[buf][wave * 32 + tt * 8][0],
                                                 16, 0, 0);
            }
        } else {
#pragma unroll
            for (int tt = 0; tt < 4; ++tt) {
                const float* src =
                    Af0 + (size_t)(rowBase + wave * 32 + tt * 8 + lrow) * K + t * 64 + scol;
                ra[tt][0] = *reinterpret_cast<const float4*>(src);
                ra[tt][1] = *reinterpret_cast<const float4*>(src + 4);
            }
            if constexpr (AMODE == 2) {
#pragma unroll
                for (int tt = 0; tt < 4; ++tt) {
                    const float* src =
                        Af1 + (size_t)(rowBase + wave * 32 + tt * 8 + lrow) * K + t * 64 + scol;
                    rb[tt][0] = *reinterpret_cast<const float4*>(src);
                    rb[tt][1] = *reinterpret_cast<const float4*>(src + 4);
                }
            }
        }
    };
    auto issueB = [&](int t, int buf) {
#pragma unroll
        for (int tt = 0; tt < 4; ++tt) {
            const bf16_t* src =
                Bt + (size_t)(colBase + wave * 32 + tt * 8 + lrow) * K + t * 64 + scol;
            __builtin_amdgcn_global_load_lds((gau32*)src,
                                             (lau32*)&Bs[buf][wave * 32 + tt * 8][0],
                                             16, 0, 0);
        }
    };
    auto writeA = [&](int buf) {   // reg path only: cvt + swizzled LDS write
        if constexpr (AMODE != 0) {
#pragma unroll
            for (int tt = 0; tt < 4; ++tt) {
                float4 a = ra[tt][0], c = ra[tt][1];
                if constexpr (AMODE == 2) {
                    a.x += rb[tt][0].x; a.y += rb[tt][0].y;
                    a.z += rb[tt][0].z; a.w += rb[tt][0].w;
                    c.x += rb[tt][1].x; c.y += rb[tt][1].y;
                    c.z += rb[tt][1].z; c.w += rb[tt][1].w;
                }
                *reinterpret_cast<bf16x8*>(
                    &As[buf][wave * 32 + tt * 8 + lrow][(lane & 7) * 8]) = cvt8(a, c);
            }
        }
    };

    // ---- prologue: tile 0 -> buf 0 ----
    issueA(0, 0);
    issueB(0, 0);
    writeA(0);
    __syncthreads();

    for (int t = 0; t < nt; ++t) {
        const int c = t & 1, n = c ^ 1;
        if (t + 1 < nt) {
            issueA(t + 1, n);
            issueB(t + 1, n);
        }
        // ---- compute tile t from buf c ----
#pragma unroll
        for (int ks = 0; ks < 2; ++ks) {
            const int gk = ((ks * 4 + fq) ^ (fr & 7)) * 8;  // swizzled read granule
            bf16x8 af[4], bfr[4];
#pragma unroll
            for (int i = 0; i < 4; ++i)
                af[i] = *reinterpret_cast<const bf16x8*>(&As[c][wm + i * 16 + fr][gk]);
#pragma unroll
            for (int j = 0; j < 4; ++j)
                bfr[j] = *reinterpret_cast<const bf16x8*>(&Bs[c][wn + j * 16 + fr][gk]);
#pragma unroll
            for (int i = 0; i < 4; ++i)
#pragma unroll
                for (int j = 0; j < 4; ++j)
                    acc[i][j] = __builtin_amdgcn_mfma_f32_16x16x32_bf16(af[i], bfr[j],
                                                                        acc[i][j], 0, 0, 0);
        }
        if (t + 1 < nt) {
            writeA(n);          // vmcnt waits for ra/rb land here, after MFMA
            __syncthreads();    // drains gload_lds; publishes buf n
        }
    }

    if (PERM_V) {
        const int lbase = colBase + wn + fr * 4;
        const float bv0 = bias[lbase], bv1 = bias[lbase + 1];
        const float bv2 = bias[lbase + 2], bv3 = bias[lbase + 3];
        const int hh = (lbase >> 5) & 7;
        const int dbase = lbase & 31;
        unsigned char* outp = (unsigned char*)Cout;
#pragma unroll
        for (int i = 0; i < 4; ++i) {
#pragma unroll
            for (int r = 0; r < 4; ++r) {
                const int row = rowBase + wm + i * 16 + fq * 4 + r;
                const int lv = row >> 14, cell = row & 16383;
                const int y = cell >> 7, x = cell & 127;
                uint32_t pk = __builtin_amdgcn_cvt_pk_fp8_f32(
                    acc[i][0][r] + bv0, acc[i][1][r] + bv1, 0, false);
                pk = (uint32_t)__builtin_amdgcn_cvt_pk_fp8_f32(
                    acc[i][2][r] + bv2, acc[i][3][r] + bv3, pk, true);
                *reinterpret_cast<uint32_t*>(
                    outp + (size_t)(lv * NHEADS + hh) * MAPB
                         + (size_t)(y + 1) * ROWB + (x + 1) * CELLB + dbase) = pk;
            }
        }
        return;
    }

    // epilogue: D[row = fq*4 + r][col = fr] per 16x16 tile
#pragma unroll
    for (int j = 0; j < 4; ++j) {
        const int col = colBase + wn + j * 16 + fr;
        const float bv = (col < Nsplit) ? bias[col] : bias2[col - Nsplit];
#pragma unroll
        for (int i = 0; i < 4; ++i) {
#pragma unroll
            for (int r = 0; r < 4; ++r) {
                const int row = rowBase + wm + i * 16 + fq * 4 + r;
                float vv = acc[i][j][r] + bv;
                if (ADD_SRC) vv += addsrc[(size_t)row * N + col];
                if (OUT_BF16)
                    ((bf16_t*)Cout)[(size_t)row * N + col] = f2b(vv);
                else
                    ((float*)Cout)[(size_t)row * N + col] = vv;
            }
        }
    }
}

// ---------------------------------------------------------------------------
// Fused projections straight from fp32 inputs (conversion fused into A-stage).
// blocks 0..511: value @ Wt_val -> padded fp8 v2 (permuted cols)
// blocks 512..895: (query+query_pos) @ [W_off|W_attn] -> cbuf (bf16)
// ---------------------------------------------------------------------------
__global__ __launch_bounds__(256, 2) void fused_proj_k(const float* __restrict__ value,
                                                       const float* __restrict__ query,
                                                       const float* __restrict__ query_pos,
                                                       const bf16_t* __restrict__ Wt_val,
                                                       const bf16_t* __restrict__ Wt_qa,
                                                       const float* __restrict__ b_val,
                                                       const float* __restrict__ b_off,
                                                       const float* __restrict__ b_attn,
                                                       unsigned char* __restrict__ v2,
                                                       bf16_t* __restrict__ cbuf) {
    __shared__ __align__(16) bf16_t As[2][128][64];
    __shared__ __align__(16) bf16_t Bs[2][128][64];
    const int b = blockIdx.x;
    if (b < 512) {
        const int bidy = (b >> 4) * 8 + (b & 7);
        const int bidx = (b >> 3) & 1;
        gemm_body<1, true, false, true>(As, Bs, bidx, bidy, nullptr, value, nullptr,
                                        Wt_val, b_val, b_val, 256, nullptr, v2,
                                        CDIM, CDIM);
    } else {
        const int b2 = b - 512;
        const int bidy = (b2 / 24) * 8 + (b2 & 7);
        const int bidx = (b2 >> 3) % 3;
        gemm_body<2, true, false, false>(As, Bs, bidx, bidy, nullptr, query, query_pos,
                                         Wt_qa, b_off, b_attn, 256, nullptr, cbuf,
                                         NCAT, CDIM);
    }
}

// ---------------------------------------------------------------------------
// Output projection: out = tmp @ W_out + b_out + query
// 64x64 tiles -> 1024 blocks (4/CU, 16 waves/CU) for gather-latency hiding;
// dbuf LDS 32 KB. Each wave computes a 32x32 sub-tile (2x2 MFMA frags).
// ---------------------------------------------------------------------------
__global__ __launch_bounds__(256, 4) void outproj_k(const bf16_t* __restrict__ tmp,
                                                    const bf16_t* __restrict__ Wt_out,
                                                    const float* __restrict__ b_out,
                                                    const float* __restrict__ query,
                                                    float* __restrict__ out) {
    __shared__ __align__(16) bf16_t As[2][64][64];
    __shared__ __align__(16) bf16_t Bs[2][64][64];
    const int b = blockIdx.x;          // 1024
    const int bidy = b >> 2, bidx = b & 3;
    const int tid = threadIdx.x, wave = tid >> 6, lane = tid & 63;
    const int rowBase = bidy * 64, colBase = bidx * 64;
    const int wm = (wave & 1) * 32, wn = (wave >> 1) * 32;
    const int fr = lane & 15, fq = lane >> 4;
    const int lrow = lane >> 3;
    const int K = 256;

    f32x4 acc[2][2] = {};

    auto stage = [&](int t, int buf) {
#pragma unroll
        for (int p = 0; p < 2; ++p) {
            const int row = wave * 16 + p * 8 + lrow;
            const int s = ((lane & 7) ^ (row & 7)) * 8;   // swizzled k-granule
            const bf16_t* srcA = tmp + (size_t)(rowBase + row) * K + t * 64 + s;
            __builtin_amdgcn_global_load_lds((gau32*)srcA,
                                             (lau32*)&As[buf][wave * 16 + p * 8][0],
                                             16, 0, 0);
            const bf16_t* srcB = Wt_out + (size_t)(colBase + row) * K + t * 64 + s;
            __builtin_amdgcn_global_load_lds((gau32*)srcB,
                                             (lau32*)&Bs[buf][wave * 16 + p * 8][0],
                                             16, 0, 0);
        }
    };

    stage(0, 0);
    __syncthreads();
    for (int t = 0; t < 4; ++t) {
        const int c = t & 1, n = c ^ 1;
        if (t + 1 < 4) stage(t + 1, n);
#pragma unroll
        for (int ks = 0; ks < 2; ++ks) {
            const int gk = ((ks * 4 + fq) ^ (fr & 7)) * 8;
            bf16x8 af[2], bfr[2];
#pragma unroll
            for (int i = 0; i < 2; ++i)
                af[i] = *reinterpret_cast<const bf16x8*>(&As[c][wm + i * 16 + fr][gk]);
#pragma unroll
            for (int j = 0; j < 2; ++j)
                bfr[j] = *reinterpret_cast<const bf16x8*>(&Bs[c][wn + j * 16 + fr][gk]);
#pragma unroll
            for (int i = 0; i < 2; ++i)
#pragma unroll
                for (int j = 0; j < 2; ++j)
                    acc[i][j] = __builtin_amdgcn_mfma_f32_16x16x32_bf16(af[i], bfr[j],
                                                                        acc[i][j], 0, 0, 0);
        }
        if (t + 1 < 4) __syncthreads();
    }

#pragma unroll
    for (int j = 0; j < 2; ++j) {
        const int col = colBase + wn + j * 16 + fr;
        const float bv = b_out[col];
#pragma unroll
        for (int i = 0; i < 2; ++i) {
#pragma unroll
            for (int r = 0; r < 4; ++r) {
                const int row = rowBase + wm + i * 16 + fq * 4 + r;
                out[(size_t)row * CDIM + col] =
                    acc[i][j][r] + bv + query[(size_t)row * CDIM + col];
            }
        }
    }
}

// ---------------------------------------------------------------------------
// Bilinear sampling on the zero-padded fp8 map. head = blockIdx % 8 -> XCD.
// 4 threads per (q,h), 8 dims each (uint2 taps): doubles resident waves for
// gather-latency hiding; lanes ck=0..3 read consecutive 8B of one 32B cell
// so L2 line traffic is unchanged. Clamped taps land on zero cells.
// ---------------------------------------------------------------------------
__device__ __forceinline__ void acc_tap2(uint2 u, float w, f32x2* acc2) {
    acc2[0] += __builtin_amdgcn_cvt_pk_f32_fp8((int)u.x, false) * w;
    acc2[1] += __builtin_amdgcn_cvt_pk_f32_fp8((int)u.x, true)  * w;
    acc2[2] += __builtin_amdgcn_cvt_pk_f32_fp8((int)u.y, false) * w;
    acc2[3] += __builtin_amdgcn_cvt_pk_f32_fp8((int)u.y, true)  * w;
}

__global__ __launch_bounds__(256, 8) void sample_k(const unsigned char* __restrict__ v2,
                                                   const bf16_t* __restrict__ cbuf,
                                                   const float* __restrict__ refp,
                                                   bf16_t* __restrict__ tmp) {
    const int b    = blockIdx.x;      // 2048 blocks
    const int h    = b & 7;           // head -> XCD (round-robin dispatch)
    const int qblk = b >> 3;          // 0..255
    const int tid  = threadIdx.x;
    const int qloc = tid >> 2;        // 0..63
    const int ck   = tid & 3;         // 8-dim quarter
    const int q    = qblk * 64 + qloc;

    const bf16_t* qrow = cbuf + (size_t)q * NCAT;
    const float4 rp = *reinterpret_cast<const float4*>(refp + (size_t)q * 4);

    // ---- softmax over the 16 logits of (q,h), in-register ----
    const bf16_t* attp = qrow + 256 + h * 16;
    bf16x8 A0 = *reinterpret_cast<const bf16x8*>(attp);
    bf16x8 A1 = *reinterpret_cast<const bf16x8*>(attp + 8);
    float e[16];
#pragma unroll
    for (int i = 0; i < 8; ++i) { e[i] = (float)A0[i]; e[8 + i] = (float)A1[i]; }
    float m = e[0];
#pragma unroll
    for (int i = 1; i < 16; ++i) m = fmaxf(m, e[i]);
    float s = 0.f;
#pragma unroll
    for (int i = 0; i < 16; ++i) { e[i] = __expf(e[i] - m); s += e[i]; }
    const float inv = 1.f / s;
#pragma unroll
    for (int i = 0; i < 16; ++i) e[i] *= inv;

    f32x2 acc2[4] = {};

#pragma unroll
    for (int l = 0; l < NLVL; ++l) {
        const float bx = (l == 0 ? rp.x : rp.z) * (float)WWID - 0.5f;
        const float by = (l == 0 ? rp.y : rp.w) * (float)HH - 0.5f;
        // +131 cells folds the (+1,+1) pad shift into the base
        const unsigned char* base = v2 + (size_t)(l * NHEADS + h) * MAPB
                                       + 131 * CELLB + ck * 8;
        const bf16_t* offp = qrow + h * 32 + l * 16;
        bf16x8 o0 = *reinterpret_cast<const bf16x8*>(offp);
        bf16x8 o1 = *reinterpret_cast<const bf16x8*>(offp + 8);
        float ox[8], oy[8];
#pragma unroll
        for (int i = 0; i < 4; ++i) {
            ox[i]     = (float)o0[2 * i];  oy[i]     = (float)o0[2 * i + 1];
            ox[4 + i] = (float)o1[2 * i];  oy[4 + i] = (float)o1[2 * i + 1];
        }

#pragma unroll
        for (int p = 0; p < NPTS; ++p) {
            const float px = bx + ox[p];
            const float py = by + oy[p];
            const float w  = e[l * 8 + p];
            const float x0f = floorf(px), y0f = floorf(py);
            const int x0 = (int)x0f, y0 = (int)y0f;
            const float wx1 = px - x0f, wy1 = py - y0f;
            const float wx0 = 1.f - wx1, wy0 = 1.f - wy1;
            const int x0c = min(max(x0, -1), 128);
            const int x1c = min(max(x0 + 1, -1), 128);
            const int y0c = min(max(y0, -1), 128);
            const int y1c = min(max(y0 + 1, -1), 128);
            const unsigned char* r0 = base + y0c * ROWB;
            const unsigned char* r1 = base + y1c * ROWB;
            uint2 u00 = *reinterpret_cast<const uint2*>(r0 + x0c * CELLB);
            uint2 u10 = *reinterpret_cast<const uint2*>(r0 + x1c * CELLB);
            uint2 u01 = *reinterpret_cast<const uint2*>(r1 + x0c * CELLB);
            uint2 u11 = *reinterpret_cast<const uint2*>(r1 + x1c * CELLB);
            const float wy0w = w * wy0, wy1w = w * wy1;
            acc_tap2(u00, wy0w * wx0, acc2);
            acc_tap2(u10, wy0w * wx1, acc2);
            acc_tap2(u01, wy1w * wx0, acc2);
            acc_tap2(u11, wy1w * wx1, acc2);
        }
    }

    bf16x8 ov;
#pragma unroll
    for (int i = 0; i < 4; ++i) {
        ov[2 * i]     = f2b(acc2[i].x);
        ov[2 * i + 1] = f2b(acc2[i].y);
    }
    bf16_t* op = tmp + (size_t)q * CDIM + h * DHEAD + ck * 8;
    *reinterpret_cast<bf16x8*>(op) = ov;
}

// ---------------------------------------------------------------------------
extern "C" void kernel_launch(void* const* d_in, const int* in_sizes, int n_in,
                              void* d_out, int out_size, void* d_ws, size_t ws_size,
                              hipStream_t stream) {
    const float* query     = (const float*)d_in[0];
    const float* query_pos = (const float*)d_in[1];
    const float* value     = (const float*)d_in[2];
    const float* refp      = (const float*)d_in[3];
    // d_in[4] spatial_shapes: static 128x128, hard-coded
    const float* W_off  = (const float*)d_in[5];
    const float* b_off  = (const float*)d_in[6];
    const float* W_attn = (const float*)d_in[7];
    const float* b_attn = (const float*)d_in[8];
    const float* W_val  = (const float*)d_in[9];
    const float* b_val  = (const float*)d_in[10];
    const float* W_out  = (const float*)d_in[11];
    const float* b_out  = (const float*)d_in[12];
    float* out = (float*)d_out;

    char* ws = (char*)d_ws;
    unsigned char* v2 = (unsigned char*)(ws);             //  8,654,848 B (padded fp8)
    bf16_t* cbuf    = (bf16_t*)(ws + 8654848);            // 12,582,912 B (16384x384 bf16)
    bf16_t* tmp     = (bf16_t*)(ws + 21237760);           //  8,388,608 B
    bf16_t* Wt_val  = (bf16_t*)(ws + 29626368);           //    131,072 B (col-permuted)
    bf16_t* Wt_qa   = (bf16_t*)(ws + 29757440);           //    196,608 B (384x256)
    bf16_t* Wt_out  = (bf16_t*)(ws + 29954048);           //    131,072 B
    // total 30,085,120 B

    // border-zero v2 + transpose weights (tiny)
    prep_k<<<BORDER_BLKS + TRANS_BLKS, 256, 0, stream>>>(
        W_val, W_off, W_attn, W_out, v2, Wt_val, Wt_qa, Wt_out);
    // v2 (padded fp8 per-head maps) + cbuf (off|attn logits, bf16),
    // fp32->bf16 conversion fused into A staging, 2-phase pipelined
    fused_proj_k<<<896, 256, 0, stream>>>(value, query, query_pos,
                                          Wt_val, Wt_qa, b_val, b_off, b_attn,
                                          v2, cbuf);
    // softmax (in-register) + bilinear sampling -> tmp (16384 x 256) bf16
    sample_k<<<2048, 256, 0, stream>>>(v2, cbuf, refp, tmp);
    // out = tmp @ W_out + b_out + query (identity)
    outproj_k<<<1024, 256, 0, stream>>>(tmp, Wt_out, b_out, query, out);
}